// Round 1
// baseline (215.203 us; speedup 1.0000x reference)
//
#include <hip/hip_runtime.h>
#include <stdint.h>

#define BATCH 8
#define HIN   28
#define CH    32
#define HO    14
#define NIN   784   // 28*28
#define NOUT  196   // 14*14

// Kernel A: one thread per (b, output-window p).
// Computes per-channel max (-> mu_out) and argmax position, and builds
// mask[b*NIN + i] : bit c set iff input flat position i is channel c's argmax
// for its window. Every thread owns a disjoint 2x2 window -> writes 4 mask
// words with no atomics; all 784 positions per b are covered every call.
__global__ void pool_argmax_kernel(const float* __restrict__ mu_in,
                                   float* __restrict__ mu_out,
                                   uint32_t* __restrict__ mask) {
    int t = blockIdx.x * blockDim.x + threadIdx.x;
    if (t >= BATCH * NOUT) return;
    int b  = t / NOUT;
    int p  = t - b * NOUT;
    int py = p / HO;
    int px = p - py * HO;
    int iy0 = py * 2, ix0 = px * 2;
    const float* base = mu_in + (((size_t)b * HIN + iy0) * HIN + ix0) * CH;
    float* outp = mu_out + (size_t)(b * NOUT + p) * CH;

    uint32_t m0 = 0, m1 = 0, m2 = 0, m3 = 0;
    for (int c = 0; c < CH; ++c) {
        float v0 = base[c];                 // (dy=0,dx=0)
        float v1 = base[CH + c];            // (dy=0,dx=1)
        float v2 = base[HIN * CH + c];      // (dy=1,dx=0)
        float v3 = base[HIN * CH + CH + c]; // (dy=1,dx=1)
        float best = v0; int k = 0;
        if (v1 > best) { best = v1; k = 1; }   // strict > keeps first max (TF tie rule)
        if (v2 > best) { best = v2; k = 2; }
        if (v3 > best) { best = v3; k = 3; }
        outp[c] = best;
        uint32_t bit = 1u << c;
        if (k == 0)      m0 |= bit;
        else if (k == 1) m1 |= bit;
        else if (k == 2) m2 |= bit;
        else             m3 |= bit;
    }
    int i0 = iy0 * HIN + ix0;
    uint32_t* mb = mask + b * NIN;
    mb[i0]           = m0;
    mb[i0 + 1]       = m1;
    mb[i0 + HIN]     = m2;
    mb[i0 + HIN + 1] = m3;
}

// Kernel B: stream Sigma_in once, fully coalesced, one float4 (4 channels) per
// thread. An element (b,i,j,c) belongs to Sigma_out[b, pool(i), pool(j), c]
// iff maskbit(b,i,c) && maskbit(b,j,c). Skip the 16B load entirely when none
// of the 4 channels is selected (~77% of threads).
__global__ __launch_bounds__(256) void sigma_gather_kernel(
        const float4* __restrict__ sigma_in,
        const uint32_t* __restrict__ mask,
        float* __restrict__ sigma_out) {
    uint32_t g = blockIdx.x * 256u + threadIdx.x;
    const uint32_t NW = (uint32_t)BATCH * NIN * NIN * (CH / 4);  // 39,337,984
    if (g >= NW) return;

    uint32_t c4  = g & 7u;         // which group of 4 channels
    uint32_t rem = g >> 3;         // (b*NIN + i)*NIN + j
    uint32_t j   = rem % NIN;
    uint32_t bi  = rem / NIN;      // b*NIN + i
    uint32_t i   = bi % NIN;
    uint32_t b   = bi / NIN;

    uint32_t mi  = mask[bi];
    uint32_t mj  = mask[b * NIN + j];
    uint32_t sel = ((mi & mj) >> (c4 * 4u)) & 0xFu;
    if (sel == 0u) return;

    float4 v = sigma_in[g];

    uint32_t iy = i / HIN, ix = i - iy * HIN;
    uint32_t jy = j / HIN, jx = j - jy * HIN;
    uint32_t p  = (iy >> 1) * HO + (ix >> 1);
    uint32_t q  = (jy >> 1) * HO + (jx >> 1);

    float* outp = sigma_out + ((size_t)(b * NOUT + p) * NOUT + q) * CH + c4 * 4u;
    if (sel & 1u) outp[0] = v.x;
    if (sel & 2u) outp[1] = v.y;
    if (sel & 4u) outp[2] = v.z;
    if (sel & 8u) outp[3] = v.w;
}

extern "C" void kernel_launch(void* const* d_in, const int* in_sizes, int n_in,
                              void* d_out, int out_size, void* d_ws, size_t ws_size,
                              hipStream_t stream) {
    const float* mu_in    = (const float*)d_in[0];
    const float* sigma_in = (const float*)d_in[1];

    float* mu_out    = (float*)d_out;                         // 8*14*14*32 = 50176 floats
    float* sigma_out = (float*)d_out + BATCH * NOUT * CH;     // 8*196*196*32 floats

    uint32_t* mask = (uint32_t*)d_ws;                         // 8*784 u32 = 25 KB

    {
        int total  = BATCH * NOUT;               // 1568
        int block  = 256;
        int blocks = (total + block - 1) / block;
        pool_argmax_kernel<<<blocks, block, 0, stream>>>(mu_in, mu_out, mask);
    }
    {
        uint32_t NW = (uint32_t)BATCH * NIN * NIN * (CH / 4); // 39,337,984
        int block   = 256;
        uint32_t blocks = (NW + block - 1) / block;           // 153,664
        sigma_gather_kernel<<<blocks, block, 0, stream>>>(
            (const float4*)sigma_in, mask, sigma_out);
    }
}

// Round 2
// 166.554 us; speedup vs baseline: 1.2921x; 1.2921x over previous
//
#include <hip/hip_runtime.h>
#include <stdint.h>

#define BATCH 8
#define HIN   28
#define CH    32
#define HO    14
#define NIN   784   // 28*28
#define NOUT  196   // 14*14

// Kernel A: one thread per (b, output-window p).
// Per channel: max over the 2x2 window -> mu_out; argmax k in (dy,dx) row-major
// order (first-match ties via strict >, matching TF/jnp.argmax). Pack k (2 bits
// per channel) into one uint64 per (b,p) -> kpack, 1568*8B = 12.5KB in d_ws.
__global__ void pool_argmax_kernel(const float* __restrict__ mu_in,
                                   float* __restrict__ mu_out,
                                   unsigned long long* __restrict__ kpack) {
    int t = blockIdx.x * blockDim.x + threadIdx.x;
    if (t >= BATCH * NOUT) return;
    int b  = t / NOUT;
    int p  = t - b * NOUT;
    int py = p / HO;
    int px = p - py * HO;
    int iy0 = py * 2, ix0 = px * 2;
    const float* base = mu_in + (((size_t)b * HIN + iy0) * HIN + ix0) * CH;
    float* outp = mu_out + (size_t)t * CH;

    unsigned long long kp = 0ull;
    #pragma unroll
    for (int c = 0; c < CH; ++c) {
        float v0 = base[c];                 // (dy=0,dx=0)
        float v1 = base[CH + c];            // (dy=0,dx=1)
        float v2 = base[HIN * CH + c];      // (dy=1,dx=0)
        float v3 = base[HIN * CH + CH + c]; // (dy=1,dx=1)
        float best = v0; int k = 0;
        if (v1 > best) { best = v1; k = 1; }   // strict > keeps first max
        if (v2 > best) { best = v2; k = 2; }
        if (v3 > best) { best = v3; k = 3; }
        outp[c] = best;
        kp |= (unsigned long long)k << (2 * c);
    }
    kpack[t] = kp;
}

// Kernel B: output-centric gather. One thread per (b,p,q):
//   Sigma_out[b,p,q,c] = Sigma_in[b, I(b,c,p), I(b,c,q), c]
// where I is decoded from kpack. The 32 gathered scalars come from at most
// 16 (i,j) positions x 2 channel-halves; lines needed by this thread are
// needed by NO other thread (pool partition), so HBM fetch = the 64B-line
// floor. Output row (128B) is written fully coalesced by its single owner.
__global__ __launch_bounds__(256) void sigma_gather_kernel(
        const float* __restrict__ sigma_in,
        const unsigned long long* __restrict__ kpack,
        float* __restrict__ sigma_out) {
    uint32_t t = blockIdx.x * 256u + threadIdx.x;
    const uint32_t TOT = (uint32_t)BATCH * NOUT * NOUT;  // 307,328
    if (t >= TOT) return;

    uint32_t q  = t % NOUT;
    uint32_t bp = t / NOUT;        // b*NOUT + p
    uint32_t p  = bp % NOUT;
    uint32_t b  = bp / NOUT;

    unsigned long long kp = kpack[bp];
    unsigned long long kq = kpack[b * NOUT + q];

    uint32_t py = p / HO, px = p - py * HO;
    uint32_t qy = q / HO, qx = q - qy * HO;
    uint32_t iy0 = 2u * py, ix0 = 2u * px;
    uint32_t jy0 = 2u * qy, jx0 = 2u * qx;

    const float* sb = sigma_in + (size_t)b * NIN * NIN * CH;

    float out[CH];
    #pragma unroll
    for (int c = 0; c < CH; ++c) {
        uint32_t kpc = ((uint32_t)(kp >> (2 * c))) & 3u;
        uint32_t kqc = ((uint32_t)(kq >> (2 * c))) & 3u;
        uint32_t i = (iy0 + (kpc >> 1)) * HIN + ix0 + (kpc & 1u);
        uint32_t j = (jy0 + (kqc >> 1)) * HIN + jx0 + (kqc & 1u);
        out[c] = sb[((size_t)i * NIN + j) * CH + c];
    }

    float4* o4 = (float4*)(sigma_out + (size_t)t * CH);
    #pragma unroll
    for (int g = 0; g < CH / 4; ++g)
        o4[g] = make_float4(out[4 * g], out[4 * g + 1],
                            out[4 * g + 2], out[4 * g + 3]);
}

extern "C" void kernel_launch(void* const* d_in, const int* in_sizes, int n_in,
                              void* d_out, int out_size, void* d_ws, size_t ws_size,
                              hipStream_t stream) {
    const float* mu_in    = (const float*)d_in[0];
    const float* sigma_in = (const float*)d_in[1];

    float* mu_out    = (float*)d_out;                      // 8*14*14*32 floats
    float* sigma_out = (float*)d_out + BATCH * NOUT * CH;  // 8*196*196*32 floats

    unsigned long long* kpack = (unsigned long long*)d_ws; // 1568 * 8B

    {
        int total  = BATCH * NOUT;               // 1568
        int block  = 256;
        int blocks = (total + block - 1) / block;
        pool_argmax_kernel<<<blocks, block, 0, stream>>>(mu_in, mu_out, kpack);
    }
    {
        uint32_t TOT = (uint32_t)BATCH * NOUT * NOUT;      // 307,328
        int block    = 256;
        uint32_t blocks = (TOT + block - 1) / block;       // 1201
        sigma_gather_kernel<<<blocks, block, 0, stream>>>(
            sigma_in, kpack, sigma_out);
    }
}